// Round 17
// baseline (114.031 us; speedup 1.0000x reference)
//
#include <hip/hip_runtime.h>
#include <hip/hip_bf16.h>

#define S_LEN 2048
#define NH 16
#define HD 64
#define DM 1024
#define BATCH 2
#define M_ROWS (BATCH * S_LEN)  // 4096
#define SCALE2 0.18033688011112043f  /* 0.125 * log2(e) */
#define M2FIX 8.0f

typedef float f32x4 __attribute__((ext_vector_type(4)));
typedef float f32x16 __attribute__((ext_vector_type(16)));
typedef __bf16 bf16x8 __attribute__((ext_vector_type(8)));
typedef short short8 __attribute__((ext_vector_type(8)));

__device__ __forceinline__ unsigned short f2bf(float f) {
  unsigned u = __builtin_bit_cast(unsigned, f);
  u += 0x7FFFu + ((u >> 16) & 1u);
  return (unsigned short)(u >> 16);
}

__device__ __forceinline__ f32x4 mfma16(bf16x8 a, bf16x8 b, f32x4 c) {
  return __builtin_amdgcn_mfma_f32_16x16x32_bf16(a, b, c, 0, 0, 0);
}

__device__ __forceinline__ f32x16 mfma32(bf16x8 a, bf16x8 b, f32x16 c) {
  return __builtin_amdgcn_mfma_f32_32x32x16_bf16(a, b, c, 0, 0, 0);
}

__device__ __forceinline__ void gload_lds16(const void* g, void* l) {
  __builtin_amdgcn_global_load_lds(
      (const __attribute__((address_space(1))) void*)g,
      (__attribute__((address_space(3))) void*)l, 16, 0, 0);
}

// ---------------- cast x -> bf16 (vectorized) ----------------
__global__ __launch_bounds__(256) void cast_bf16_kernel(
    const float* __restrict__ in, unsigned short* __restrict__ out) {
  int i = blockIdx.x * 256 + threadIdx.x;
  const float4* p = (const float4*)in;
  float4 f0 = p[i * 2], f1 = p[i * 2 + 1];
  short8 o;
  o[0] = (short)f2bf(f0.x); o[1] = (short)f2bf(f0.y);
  o[2] = (short)f2bf(f0.z); o[3] = (short)f2bf(f0.w);
  o[4] = (short)f2bf(f1.x); o[5] = (short)f2bf(f1.y);
  o[6] = (short)f2bf(f1.z); o[7] = (short)f2bf(f1.w);
  ((short8*)out)[i] = o;
}

// ---------------- transpose + cast weights: Wt[n][k] = bf16(W[k][n]) ----------------
__global__ __launch_bounds__(256) void transpose_cast_kernel(
    const float* __restrict__ W0, const float* __restrict__ W1,
    const float* __restrict__ W2, const float* __restrict__ W3,
    unsigned short* __restrict__ out) {
  int z = blockIdx.z;
  const float* W = (z == 0) ? W0 : (z == 1) ? W1 : (z == 2) ? W2 : W3;
  __shared__ float tile[32][33];
  int tx = threadIdx.x & 31, ty = threadIdx.x >> 5;
  int bx = blockIdx.x * 32, by = blockIdx.y * 32;
#pragma unroll
  for (int i = 0; i < 4; ++i)
    tile[ty + i * 8][tx] = W[(size_t)(by + ty + i * 8) * DM + bx + tx];
  __syncthreads();
  unsigned short* o = out + (size_t)z * DM * DM;
#pragma unroll
  for (int i = 0; i < 4; ++i)
    o[(size_t)(bx + ty + i * 8) * DM + by + tx] = f2bf(tile[tx][ty + i * 8]);
}

// ---------------- QKV GEMM: 256^2, BK=64, 4-phase deep pipeline -------------------
// 512 thr (8 waves, 2M x 4N; per-wave 128x64). LDS 128KB: A[slot2][half2][16KB]
// then B same at +64KB. Phases per K-tile j (slot p=j&1), quadrants
// (M0N0),(M0N1),(M1N1),(M1N0); A halves die at P3, B at P4 -> stage points:
// P1 stages B(tile j+1 -> slot p^1), P4 stages A(tile j+2 -> slot p);
// counted vmcnt(4) at P4 only (tail: vmcnt(0)). st_16x32 swizzle both-sides:
// linear LDS dest + inverse-swizzled global k-chunk + lane-constant read XOR.
__global__ __launch_bounds__(512, 2) void gemm_qkv256_kernel(
    const unsigned short* __restrict__ A, const unsigned short* __restrict__ Bt,
    unsigned short* __restrict__ Cb, const float* __restrict__ bQ,
    const float* __restrict__ bK, const float* __restrict__ bV) {
  const int t = threadIdx.x, lane = t & 63;
  const int wid = t >> 6, wr = wid >> 2, wc = wid & 3;
  const int r16 = lane & 15, g = lane >> 4;
  const int K = 1024, nt = 16;

  const int lid = blockIdx.x;
  const int xcd = lid & 7, idx = lid >> 3;  // 0..23
  const int by = xcd * 2 + (idx >= 12);
  const int bx = (idx >= 12) ? idx - 12 : idx;
  const int m0 = by * 256, n0 = bx * 256;

  __shared__ __align__(16) char LB[131072];

  // staging: per half (16KB), thread t writes chunks t and t+512 (linear dest).
  // stored chunk c holds logical k-chunk (c&7)^(((c>>5)&1)<<1)  [bit9->bit5 XOR]
  const int r0 = t >> 3;                                  // row 0..63 (+64 for c1)
  const int gk = ((t & 7) ^ (((t >> 5) & 1) << 1)) * 8;   // element offset in k

  auto stageA = [&](int s, int kt) {
#pragma unroll
    for (int h = 0; h < 2; ++h) {
      char* dst = LB + (s * 2 + h) * 16384 + t * 16;
      const unsigned short* src = A + (size_t)(m0 + h * 128 + r0) * K + kt * 64 + gk;
      gload_lds16(src, dst);
      gload_lds16(src + (size_t)64 * K, dst + 8192);
    }
  };
  auto stageB = [&](int s, int kt) {
#pragma unroll
    for (int h = 0; h < 2; ++h) {
      char* dst = LB + 65536 + (s * 2 + h) * 16384 + t * 16;
      const unsigned short* src = Bt + (size_t)(n0 + h * 128 + r0) * K + kt * 64 + gk;
      gload_lds16(src, dst);
      gload_lds16(src + (size_t)64 * K, dst + 8192);
    }
  };

  // read-side: byte = localrow*128 + ks*64 + g*16, XOR lane-constant (r16&4)<<3
  const int aoff = (r16 * 128 + g * 16) ^ ((r16 & 4) << 3);

  f32x4 acc[8][4] = {};

  // prologue: A(t0)->s0, B(t0)->s0, A(t1)->s1  (12 loads); t0 landed after vmcnt(4)
  stageA(0, 0);
  stageB(0, 0);
  stageA(1, 1);
  asm volatile("s_waitcnt vmcnt(4)" ::: "memory");
  __builtin_amdgcn_s_barrier();

#pragma unroll 1
  for (int j = 0; j < 16; ++j) {
    const int p = j & 1;
    const char* Ah = LB + (p * 2 + wr) * 16384;
    const char* Bh = LB + 65536 + (p * 2 + (wc >> 1)) * 16384 + (wc & 1) * 8192;

    bf16x8 afr[4][2], bfr[2][2], b2[2][2];

    // ---- P1: quadrant (M0, N0); stage B(j+1) ----
#pragma unroll
    for (int mi = 0; mi < 4; ++mi)
#pragma unroll
      for (int ks = 0; ks < 2; ++ks)
        afr[mi][ks] = *(const bf16x8*)(Ah + mi * 2048 + ks * 64 + aoff);
#pragma unroll
    for (int ni = 0; ni < 2; ++ni)
#pragma unroll
      for (int ks = 0; ks < 2; ++ks)
        bfr[ni][ks] = *(const bf16x8*)(Bh + ni * 2048 + ks * 64 + aoff);
    if (j + 1 < nt) stageB(p ^ 1, j + 1);
    __builtin_amdgcn_s_barrier();
    asm volatile("s_waitcnt lgkmcnt(0)" ::: "memory");
    __builtin_amdgcn_s_setprio(1);
#pragma unroll
    for (int mi = 0; mi < 4; ++mi)
#pragma unroll
      for (int ni = 0; ni < 2; ++ni)
#pragma unroll
        for (int ks = 0; ks < 2; ++ks)
          acc[mi][ni] = mfma16(afr[mi][ks], bfr[ni][ks], acc[mi][ni]);
    __builtin_amdgcn_s_setprio(0);
    __builtin_amdgcn_s_barrier();

    // ---- P2: quadrant (M0, N1) ----
#pragma unroll
    for (int ni = 0; ni < 2; ++ni)
#pragma unroll
      for (int ks = 0; ks < 2; ++ks)
        b2[ni][ks] = *(const bf16x8*)(Bh + 4096 + ni * 2048 + ks * 64 + aoff);
    __builtin_amdgcn_s_barrier();
    asm volatile("s_waitcnt lgkmcnt(0)" ::: "memory");
    __builtin_amdgcn_s_setprio(1);
#pragma unroll
    for (int mi = 0; mi < 4; ++mi)
#pragma unroll
      for (int ni = 0; ni < 2; ++ni)
#pragma unroll
        for (int ks = 0; ks < 2; ++ks)
          acc[mi][2 + ni] = mfma16(afr[mi][ks], b2[ni][ks], acc[mi][2 + ni]);
    __builtin_amdgcn_s_setprio(0);
    __builtin_amdgcn_s_barrier();

    // ---- P3: quadrant (M1, N1) ----
#pragma unroll
    for (int mi = 0; mi < 4; ++mi)
#pragma unroll
      for (int ks = 0; ks < 2; ++ks)
        afr[mi][ks] = *(const bf16x8*)(Ah + 8192 + mi * 2048 + ks * 64 + aoff);
    __builtin_amdgcn_s_barrier();
    asm volatile("s_waitcnt lgkmcnt(0)" ::: "memory");
    __builtin_amdgcn_s_setprio(1);
#pragma unroll
    for (int mi = 0; mi < 4; ++mi)
#pragma unroll
      for (int ni = 0; ni < 2; ++ni)
#pragma unroll
        for (int ks = 0; ks < 2; ++ks)
          acc[4 + mi][2 + ni] = mfma16(afr[mi][ks], b2[ni][ks], acc[4 + mi][2 + ni]);
    __builtin_amdgcn_s_setprio(0);
    __builtin_amdgcn_s_barrier();

    // ---- P4: quadrant (M1, N0); stage A(j+2); counted vmcnt ----
#pragma unroll
    for (int ni = 0; ni < 2; ++ni)
#pragma unroll
      for (int ks = 0; ks < 2; ++ks)
        bfr[ni][ks] = *(const bf16x8*)(Bh + ni * 2048 + ks * 64 + aoff);
    if (j + 2 < nt) stageA(p, j + 2);
    __builtin_amdgcn_s_barrier();
    asm volatile("s_waitcnt lgkmcnt(0)" ::: "memory");
    __builtin_amdgcn_s_setprio(1);
#pragma unroll
    for (int mi = 0; mi < 4; ++mi)
#pragma unroll
      for (int ni = 0; ni < 2; ++ni)
#pragma unroll
        for (int ks = 0; ks < 2; ++ks)
          acc[4 + mi][ni] = mfma16(afr[mi][ks], bfr[ni][ks], acc[4 + mi][ni]);
    __builtin_amdgcn_s_setprio(0);
    if (j + 2 < nt) {
      asm volatile("s_waitcnt vmcnt(4)" ::: "memory");
    } else {
      asm volatile("s_waitcnt vmcnt(0)" ::: "memory");
    }
    __builtin_amdgcn_s_barrier();
  }

  // ---------------- epilogue (validated in r14/r15) ----------------
  const int bufq = n0 >> 10;  // 0=Q 1=K 2=V
  if (bufq < 2) {
    const float* bp = bufq ? bK : bQ;
    const float sc = bufq ? 1.0f : SCALE2;
#pragma unroll
    for (int ni = 0; ni < 4; ++ni) {
      int cn = (n0 & 1023) + wc * 64 + ni * 16 + r16;
      float bv = bp[cn];
#pragma unroll
      for (int mi = 0; mi < 8; ++mi) {
        int row = m0 + wr * 128 + mi * 16 + 4 * g;
#pragma unroll
        for (int jj = 0; jj < 4; ++jj)
          Cb[(size_t)bufq * 4194304u + (size_t)(row + jj) * 1024 + cn] =
              __builtin_bit_cast(unsigned short, (__bf16)((acc[mi][ni][jj] + bv) * sc));
      }
    }
  } else {
    // V: 256(s) x 256(hd) tile -> V^T in two 128-col passes through LDS
    unsigned short* T = (unsigned short*)LB;  // [128 cnl][264] shorts
    const int bb = m0 >> 11, s0g = m0 & 2047;
    unsigned short* Vt = Cb + 8388608u;
#pragma unroll
    for (int ph = 0; ph < 2; ++ph) {
      __syncthreads();
      if ((wc >> 1) == ph) {
#pragma unroll
        for (int ni = 0; ni < 4; ++ni) {
          int cnl = (wc & 1) * 64 + ni * 16 + r16;  // 0..127
          float bv = bV[(n0 & 1023) + ph * 128 + cnl];
#pragma unroll
          for (int mi = 0; mi < 8; ++mi) {
            int sl = wr * 128 + mi * 16 + 4 * g;
            union { __bf16 h4[4]; uint2 u; } cv;
#pragma unroll
            for (int jj = 0; jj < 4; ++jj) cv.h4[jj] = (__bf16)(acc[mi][ni][jj] + bv);
            *(uint2*)&T[cnl * 264 + sl] = cv.u;
          }
        }
      }
      __syncthreads();
#pragma unroll
      for (int q = 0; q < 8; ++q) {
        int idx2 = q * 512 + t;
        int cnl = idx2 >> 5, sch = idx2 & 31;
        int cng = (n0 & 1023) + ph * 128 + cnl;
        int hh = cng >> 6, d = cng & 63;
        short8 v = *(const short8*)&T[cnl * 264 + sch * 8];
        *(short8*)&Vt[(((size_t)((bb * 16 + hh) * 64 + d)) << 11) + s0g + sch * 8] = v;
      }
    }
  }
}

// ---------------- output-projection GEMM (r11 exact 128^2) ----------------
__global__ __launch_bounds__(256) void gemm_out_kernel(
    const unsigned short* __restrict__ A, const unsigned short* __restrict__ Bt,
    float* __restrict__ Cf, const float* __restrict__ bias0, int M, int N, int K) {
  __shared__ __align__(16) unsigned short As[3][4096];
  __shared__ __align__(16) unsigned short Bs[3][4096];
  const int t = threadIdx.x, lane = t & 63;
  const int wid = t >> 6, wr = wid >> 1, wc = wid & 1;
  const int r16 = lane & 15, g = lane >> 4;
  const int m0 = blockIdx.y * 128, n0 = blockIdx.x * 128;
  const int nk = K >> 5;

  const int n1 = t, n2 = t + 256;
  const int r1g = t >> 2, c1g = (t & 3) * 8;
  const int r2g = (t + 256) >> 2;

  const unsigned short* ap1 = A + (size_t)(m0 + r1g) * K + c1g;
  const unsigned short* ap2 = A + (size_t)(m0 + r2g) * K + c1g;
  const unsigned short* bp1 = Bt + (size_t)(n0 + r1g) * K + c1g;
  const unsigned short* bp2 = Bt + (size_t)(n0 + r2g) * K + c1g;

#define GSTAGE(s)                          \
  gload_lds16(ap1, &As[s][n1 * 8]);        \
  gload_lds16(bp1, &Bs[s][n1 * 8]);        \
  gload_lds16(ap2, &As[s][n2 * 8]);        \
  gload_lds16(bp2, &Bs[s][n2 * 8]);        \
  ap1 += 32; ap2 += 32; bp1 += 32; bp2 += 32;

  f32x4 acc[4][4] = {};
  GSTAGE(0);
  GSTAGE(1);

  for (int kt = 0; kt < nk; ++kt) {
    const int cs = kt % 3;
    if (kt + 1 < nk) {
      asm volatile("s_waitcnt vmcnt(4)" ::: "memory");
    } else {
      asm volatile("s_waitcnt vmcnt(0)" ::: "memory");
    }
    __builtin_amdgcn_s_barrier();
    if (kt + 2 < nk) { GSTAGE((kt + 2) % 3); }

    bf16x8 af[4], bfr[4];
#pragma unroll
    for (int mi = 0; mi < 4; ++mi)
      af[mi] = *(const bf16x8*)&As[cs][(wr * 64 + mi * 16 + r16) * 32 + g * 8];
#pragma unroll
    for (int ni = 0; ni < 4; ++ni)
      bfr[ni] = *(const bf16x8*)&Bs[cs][(wc * 64 + ni * 16 + r16) * 32 + g * 8];
    __builtin_amdgcn_s_setprio(1);
#pragma unroll
    for (int mi = 0; mi < 4; ++mi)
#pragma unroll
      for (int ni = 0; ni < 4; ++ni)
        acc[mi][ni] = mfma16(af[mi], bfr[ni], acc[mi][ni]);
    __builtin_amdgcn_s_setprio(0);
  }
#undef GSTAGE

#pragma unroll
  for (int ni = 0; ni < 4; ++ni) {
    int col = n0 + wc * 64 + ni * 16 + r16;
    float bv = bias0[col];
#pragma unroll
    for (int mi = 0; mi < 4; ++mi) {
      int rowb = m0 + wr * 64 + mi * 16 + 4 * g;
#pragma unroll
      for (int j = 0; j < 4; ++j)
        Cf[(size_t)(rowb + j) * N + col] = acc[mi][ni][j] + bv;
    }
  }
}

// ---------------- flash attention v11 (best, unchanged): 32x32 MFMA, kv-split -------
__global__ __launch_bounds__(256, 2) void attn_kernel(
    const unsigned short* __restrict__ Qm, const unsigned short* __restrict__ Km,
    const unsigned short* __restrict__ VtG, unsigned short* __restrict__ Om) {
  const int t = threadIdx.x, lane = t & 63, w = t >> 6;
  const int l31 = lane & 31, hi = lane >> 5;
  const int bid = blockIdx.x;
  const int xk = bid & 7, slot = bid >> 3;
  const int grp = xk * 4 + (slot >> 4);  // (b,h) group, 4 per XCD
  const int mq = slot & 15;
  const int h = grp & 15, b = grp >> 4;

  __shared__ __align__(16) char LB[71680];
  float* R = (float*)LB;
  float* ls = (float*)(LB + 69632);

  const unsigned short* Kbase = Km + (size_t)(b * S_LEN) * DM + h * HD;
  const unsigned short* Vbase = VtG + (size_t)((b * NH + h) * HD) * S_LEN;

  const int kg = ((t & 7) ^ ((t >> 3) & 7)) * 8;
  const int kr0 = t >> 3;
  const int vg = ((t & 15) ^ ((t >> 4) & 15)) * 8;
  const int vr0 = t >> 4;

  auto stage = [&](int cs, int kv0) {
    unsigned short* kd = (unsigned short*)(LB + cs * 16384) + t * 8;
    unsigned short* vd = (unsigned short*)(LB + 32768 + cs * 16384) + t * 8;
#pragma unroll
    for (int p = 0; p < 4; ++p)
      gload_lds16(Kbase + (size_t)(kv0 + kr0 + 32 * p) * DM + kg, kd + 2048 * p);
#pragma unroll
    for (int p = 0; p < 4; ++p)
      gload_lds16(Vbase + (size_t)(vr0 + 16 * p) * S_LEN + kv0 + vg, vd + 2048 * p);
  };

  for (int half = 0; half < 2; ++half) {
    const int T = half ? 31 - mq : mq;
    const int q0 = T * 64;

    bf16x8 qfr[2][4];
#pragma unroll
    for (int qt = 0; qt < 2; ++qt) {
      const unsigned short* Qp =
          Qm + (size_t)(b * S_LEN + q0 + qt * 32 + l31) * DM + h * HD;
#pragma unroll
      for (int kc = 0; kc < 4; ++kc)
        qfr[qt][kc] = *(const bf16x8*)(Qp + kc * 16 + hi * 8);
    }

    f32x16 oacc[2][2] = {};
    float lsum0 = 0.f, lsum1 = 0.f;
    const int ntk = (T >> 1) + 1;

    stage(0, 0);

    for (int kt = 0; kt < ntk; ++kt) {
      const int cs = kt & 1;
      asm volatile("s_waitcnt vmcnt(0)" ::: "memory");
      __builtin_amdgcn_s_barrier();
      if (kt + 1 < ntk) stage(cs ^ 1, (kt + 1) * 128);

      const int kv0w = kt * 128 + w * 32;
      if (kv0w <= q0 + 63) {
        const unsigned short* Ksb = (const unsigned short*)(LB + cs * 16384);
        const unsigned short* Vsb = (const unsigned short*)(LB + 32768 + cs * 16384);

        bf16x8 kf[4];
#pragma unroll
        for (int kc = 0; kc < 4; ++kc)
          kf[kc] = *(const bf16x8*)&Ksb[(w * 32 + l31) * 64 +
                                        (((hi + 2 * kc) ^ (lane & 7)) * 8)];
        bool act0 = false, act1 = false;
        bf16x8 pfr[2][2];
#pragma unroll
        for (int qt = 0; qt < 2; ++qt) {
          const bool act = (kv0w <= q0 + qt * 32 + 31);
          if (qt == 0) act0 = act; else act1 = act;
          if (!act) continue;
          f32x16 st = {};
          __builtin_amdgcn_s_setprio(1);
#pragma unroll
          for (int kc = 0; kc < 4; ++kc) st = mfma32(kf[kc], qfr[qt][kc], st);
          __builtin_amdgcn_s_setprio(0);

          const bool needmask = (kv0w + 31 > q0 + qt * 32);
          const int qg = q0 + qt * 32 + l31;
          float p[16];
          float ps = 0.f;
#pragma unroll
          for (int r = 0; r < 16; ++r) {
            int row = (r & 3) + 8 * (r >> 2) + 4 * hi;
            float v = __builtin_amdgcn_exp2f(st[r] - M2FIX);
            if (needmask && (kv0w + row > qg)) v = 0.f;
            p[r] = v;
            ps += v;
          }
          if (qt == 0) lsum0 += ps; else lsum1 += ps;

          unsigned pw[8];
#pragma unroll
          for (int r = 0; r < 8; ++r) {
            union { __bf16 h2[2]; unsigned u; } cv;
            cv.h2[0] = (__bf16)p[2 * r];
            cv.h2[1] = (__bf16)p[2 * r + 1];
            pw[r] = cv.u;
          }
          {
            auto s0 = __builtin_amdgcn_permlane32_swap(pw[0], pw[2], false, false);
            pw[0] = s0[0]; pw[2] = s0[1];
            auto s1 = __builtin_amdgcn_permlane32_swap(pw[1], pw[3], false, false);
            pw[1] = s1[0]; pw[3] = s1[1];
            auto s2 = __builtin_amdgcn_permlane32_swap(pw[4], pw[6], false, false);
            pw[4] = s2[0]; pw[6] = s2[1];
            auto s3 = __builtin_amdgcn_permlane32_swap(pw[5], pw[7], false, false);
            pw[5] = s3[0]; pw[7] = s3[1];
          }
          union { unsigned u[4]; bf16x8 v; } f0, f1;
          f0.u[0] = pw[0]; f0.u[1] = pw[1]; f0.u[2] = pw[2]; f0.u[3] = pw[3];
          f1.u[0] = pw[4]; f1.u[1] = pw[5]; f1.u[2] = pw[6]; f1.u[3] = pw[7];
          pfr[qt][0] = f0.v;
          pfr[qt][1] = f1.v;
        }

        bf16x8 vf[2][2];
#pragma unroll
        for (int dt = 0; dt < 2; ++dt)
#pragma unroll
          for (int ks = 0; ks < 2; ++ks)
            vf[dt][ks] = *(const bf16x8*)&Vsb[(dt * 32 + l31) * 128 +
                                              (((4 * w + 2 * ks + hi) ^ (lane & 15)) * 8)];
        __builtin_amdgcn_s_setprio(1);
        if (act0) {
#pragma unroll
          for (int dt = 0; dt < 2; ++dt) {
            oacc[dt][0] = mfma32(vf[dt][0], pfr[0][0], oacc[dt][0]);
            oacc[dt][0] = mfma32(vf[dt][1], pfr[0][1], oacc[dt][0]);
          }
        }
        if (act1) {
#pragma unroll
          for (int dt = 0; dt < 2; ++dt) {
            oacc[dt][1] = mfma32(vf[dt][0], pfr[1][0], oacc[dt][1]);
            oacc[dt][1] = mfma32(vf[dt][1], pfr[1][1], oacc[dt][1]);
          }
        }
        __builtin_amdgcn_s_setprio(0);
      }
    }

    __syncthreads();
    float* Rw = R + w * 4352;
#pragma unroll
    for (int dt = 0; dt < 2; ++dt)
#pragma unroll
      for (int qt = 0; qt < 2; ++qt) {
        int q = qt * 32 + l31;
#pragma unroll
        for (int r = 0; r < 16; r += 2) {
          int d = dt * 32 + ((r & 3) + 8 * (r >> 2)) + 4 * hi;
          float2 v2;
          v2.x = oacc[dt][qt][r];
          v2.y = oacc[dt][qt][r + 1];
          *(float2*)&Rw[q * 68 + d] = v2;
        }
      }
    ls[(w * 64 + l31) * 2 + hi] = lsum0;
    ls[(w * 64 + 32 + l31) * 2 + hi] = lsum1;
    __syncthreads();

    const int rq = t >> 2, dq = (t & 3) * 16;
    f32x4 a0 = {}, a1 = {}, a2 = {}, a3 = {};
#pragma unroll
    for (int w4 = 0; w4 < 4; ++w4) {
      const float* Rb = R + w4 * 4352 + rq * 68 + dq;
      a0 += *(const f32x4*)&Rb[0];
      a1 += *(const f32x4*)&Rb[4];
      a2 += *(const f32x4*)&Rb[8];
      a3 += *(const f32x4*)&Rb[12];
    }
    float s = 0.f;
#pragma unroll
    for (int w4 = 0; w4 < 4; ++w4)
      s += ls[(w4 * 64 + rq) * 2] + ls[(w4 * 64 + rq) * 2 + 1];
    float li = 1.0f / s;
    unsigned short* op = Om + (size_t)(b * S_LEN + q0 + rq) * DM + h * HD + dq;
    union { __bf16 hh[8]; uint4 u; } o0, o1;
#pragma unroll
    for (int i = 0; i < 4; ++i) {
      o0.hh[i] = (__bf16)(a0[i] * li);
      o0.hh[4 + i] = (__bf16)(a1[i] * li);
      o1.hh[i] = (__bf16)(a2[i] * li);
      o1.hh[4 + i] = (__bf16)(a3[i] * li);
    }
    *(uint4*)op = o0.u;
    *(uint4*)(op + 8) = o1.u;
    __syncthreads();
  }
}

extern "C" void kernel_launch(void* const* d_in, const int* in_sizes, int n_in,
                              void* d_out, int out_size, void* d_ws, size_t ws_size,
                              hipStream_t stream) {
  (void)in_sizes; (void)n_in; (void)out_size; (void)ws_size;
  const float* x  = (const float*)d_in[0];
  const float* WQ = (const float*)d_in[1];
  const float* WK = (const float*)d_in[2];
  const float* WV = (const float*)d_in[3];
  const float* WO = (const float*)d_in[4];
  const float* bQ = (const float*)d_in[5];
  const float* bK = (const float*)d_in[6];
  const float* bV = (const float*)d_in[7];
  const float* bO = (const float*)d_in[8];

  char* ws = (char*)d_ws;
  unsigned short* xb  = (unsigned short*)(ws);               // 8 MiB (x bf16)
  unsigned short* wt  = (unsigned short*)(ws + (8u << 20));  // 8 MiB (Wq|Wk|Wv|Wo)^T
  unsigned short* qb  = (unsigned short*)(ws + (16u << 20)); // 24 MiB (Q | K | V^T)
  unsigned short* hsb = (unsigned short*)(ws + (40u << 20)); // 8 MiB (attn out)

  cast_bf16_kernel<<<2048, 256, 0, stream>>>(x, xb);
  transpose_cast_kernel<<<dim3(32, 32, 4), 256, 0, stream>>>(WQ, WK, WV, WO, wt);
  // fused QKV projection (256^2 deep-pipeline): Q pre-scaled, V^T epilogue
  gemm_qkv256_kernel<<<192, 512, 0, stream>>>(xb, wt, qb, bQ, bK, bV);
  attn_kernel<<<512, 256, 0, stream>>>(qb, qb + 4194304u, qb + 8388608u, hsb);
  // output projection: f32 out (r11 exact)
  gemm_out_kernel<<<dim3(8, 32), 256, 0, stream>>>(
      hsb, wt + 3u * 1048576u, (float*)d_out, bO, M_ROWS, DM, DM);
}

// Round 18
// 104.047 us; speedup vs baseline: 1.0960x; 1.0960x over previous
//
#include <hip/hip_runtime.h>
#include <hip/hip_bf16.h>

#define S_LEN 2048
#define NH 16
#define HD 64
#define DM 1024
#define BATCH 2
#define M_ROWS (BATCH * S_LEN)  // 4096
#define SCALE2 0.18033688011112043f  /* 0.125 * log2(e) */
#define M2FIX 8.0f

typedef float f32x4 __attribute__((ext_vector_type(4)));
typedef float f32x16 __attribute__((ext_vector_type(16)));
typedef __bf16 bf16x8 __attribute__((ext_vector_type(8)));
typedef short short8 __attribute__((ext_vector_type(8)));

__device__ __forceinline__ unsigned short f2bf(float f) {
  unsigned u = __builtin_bit_cast(unsigned, f);
  u += 0x7FFFu + ((u >> 16) & 1u);
  return (unsigned short)(u >> 16);
}

__device__ __forceinline__ f32x4 mfma16(bf16x8 a, bf16x8 b, f32x4 c) {
  return __builtin_amdgcn_mfma_f32_16x16x32_bf16(a, b, c, 0, 0, 0);
}

__device__ __forceinline__ f32x16 mfma32(bf16x8 a, bf16x8 b, f32x16 c) {
  return __builtin_amdgcn_mfma_f32_32x32x16_bf16(a, b, c, 0, 0, 0);
}

__device__ __forceinline__ void gload_lds16(const void* g, void* l) {
  __builtin_amdgcn_global_load_lds(
      (const __attribute__((address_space(1))) void*)g,
      (__attribute__((address_space(3))) void*)l, 16, 0, 0);
}

// ---------------- cast x -> bf16 (vectorized) ----------------
__global__ __launch_bounds__(256) void cast_bf16_kernel(
    const float* __restrict__ in, unsigned short* __restrict__ out) {
  int i = blockIdx.x * 256 + threadIdx.x;  // each handles 8 elems
  const float4* p = (const float4*)in;
  float4 f0 = p[i * 2], f1 = p[i * 2 + 1];
  short8 o;
  o[0] = (short)f2bf(f0.x); o[1] = (short)f2bf(f0.y);
  o[2] = (short)f2bf(f0.z); o[3] = (short)f2bf(f0.w);
  o[4] = (short)f2bf(f1.x); o[5] = (short)f2bf(f1.y);
  o[6] = (short)f2bf(f1.z); o[7] = (short)f2bf(f1.w);
  ((short8*)out)[i] = o;
}

// ---------------- transpose + cast weights: Wt[n][k] = bf16(W[k][n]) ----------------
__global__ __launch_bounds__(256) void transpose_cast_kernel(
    const float* __restrict__ W0, const float* __restrict__ W1,
    const float* __restrict__ W2, const float* __restrict__ W3,
    unsigned short* __restrict__ out) {
  int z = blockIdx.z;
  const float* W = (z == 0) ? W0 : (z == 1) ? W1 : (z == 2) ? W2 : W3;
  __shared__ float tile[32][33];
  int tx = threadIdx.x & 31, ty = threadIdx.x >> 5;  // 32 x 8
  int bx = blockIdx.x * 32, by = blockIdx.y * 32;
#pragma unroll
  for (int i = 0; i < 4; ++i)
    tile[ty + i * 8][tx] = W[(size_t)(by + ty + i * 8) * DM + bx + tx];
  __syncthreads();
  unsigned short* o = out + (size_t)z * DM * DM;
#pragma unroll
  for (int i = 0; i < 4; ++i)
    o[(size_t)(bx + ty + i * 8) * DM + by + tx] = f2bf(tile[tx][ty + i * 8]);
}

// ---------------- GEMM: C[m][n] = sum_k A[m][k] * Bt[n][k] --------------------
// Triple-buffered staging, counted vmcnt(4), one barrier per K-step.
// MODE 0: QKV fused (N=3072). Q pre-scaled by SCALE2; V written transposed per
//         head via LDS transpose: Vt[((b*16+h)*64+d)*2048 + s].
// MODE 1: f32 out (single buffer), bias0.
template <int MODE>
__global__ __launch_bounds__(256) void gemm_bt_kernel(
    const unsigned short* __restrict__ A, const unsigned short* __restrict__ Bt,
    void* __restrict__ Cptr, const float* __restrict__ bias0,
    const float* __restrict__ bias1, const float* __restrict__ bias2,
    int M, int N, int K) {
  __shared__ __align__(16) unsigned short Sbuf[2][3][4096];  // As | Bs (contiguous)
  unsigned short (*As)[4096] = Sbuf[0];
  unsigned short (*Bs)[4096] = Sbuf[1];
  const int t = threadIdx.x, lane = t & 63;
  const int wid = t >> 6, wr = wid >> 1, wc = wid & 1;
  const int r16 = lane & 15, g = lane >> 4;
  const int m0 = blockIdx.y * 128, n0 = blockIdx.x * 128;
  const int nk = K >> 5;

  const int n1 = t, n2 = t + 256;
  const int r1g = t >> 2, c1g = (t & 3) * 8;
  const int r2g = (t + 256) >> 2;

  const unsigned short* ap1 = A + (size_t)(m0 + r1g) * K + c1g;
  const unsigned short* ap2 = A + (size_t)(m0 + r2g) * K + c1g;
  const unsigned short* bp1 = Bt + (size_t)(n0 + r1g) * K + c1g;
  const unsigned short* bp2 = Bt + (size_t)(n0 + r2g) * K + c1g;

#define GSTAGE(s)                          \
  gload_lds16(ap1, &As[s][n1 * 8]);        \
  gload_lds16(bp1, &Bs[s][n1 * 8]);        \
  gload_lds16(ap2, &As[s][n2 * 8]);        \
  gload_lds16(bp2, &Bs[s][n2 * 8]);        \
  ap1 += 32; ap2 += 32; bp1 += 32; bp2 += 32;

  f32x4 acc[4][4] = {};

  GSTAGE(0);
  GSTAGE(1);

  for (int kt = 0; kt < nk; ++kt) {
    const int cs = kt % 3;
    if (kt + 1 < nk) {
      asm volatile("s_waitcnt vmcnt(4)" ::: "memory");
    } else {
      asm volatile("s_waitcnt vmcnt(0)" ::: "memory");
    }
    __builtin_amdgcn_s_barrier();
    if (kt + 2 < nk) { GSTAGE((kt + 2) % 3); }

    bf16x8 af[4], bfr[4];
#pragma unroll
    for (int mi = 0; mi < 4; ++mi)
      af[mi] = *(const bf16x8*)&As[cs][(wr * 64 + mi * 16 + r16) * 32 + g * 8];
#pragma unroll
    for (int ni = 0; ni < 4; ++ni)
      bfr[ni] = *(const bf16x8*)&Bs[cs][(wc * 64 + ni * 16 + r16) * 32 + g * 8];
    __builtin_amdgcn_s_setprio(1);
#pragma unroll
    for (int mi = 0; mi < 4; ++mi)
#pragma unroll
      for (int ni = 0; ni < 4; ++ni)
        acc[mi][ni] = mfma16(af[mi], bfr[ni], acc[mi][ni]);
    __builtin_amdgcn_s_setprio(0);
  }
#undef GSTAGE

  if (MODE == 0) {
    unsigned short* Cb = (unsigned short*)Cptr;
    const int buf = n0 >> 10;  // whole block lies in one of Q/K/V (128 | 1024)
    if (buf < 2) {
      const float* bp = buf ? bias1 : bias0;
      const float sc = buf ? 1.0f : SCALE2;  // pre-scale Q for attn
#pragma unroll
      for (int ni = 0; ni < 4; ++ni) {
        int cn = (n0 & 1023) + wc * 64 + ni * 16 + r16;
        float bv = bp[cn];
#pragma unroll
        for (int mi = 0; mi < 4; ++mi) {
          int rowb = m0 + wr * 64 + mi * 16 + 4 * g;
#pragma unroll
          for (int j = 0; j < 4; ++j)
            Cb[(size_t)buf * 4194304u + (size_t)(rowb + j) * 1024 + cn] =
                __builtin_bit_cast(unsigned short, (__bf16)((acc[mi][ni][j] + bv) * sc));
        }
      }
    } else {
      // V: transpose the 128(s) x 128(hd) tile through LDS, then write V^T with
      // 16B stores contiguous along s.
      unsigned short* T = &Sbuf[0][0][0];  // 24576 shorts >= 128*136 = 17408
      __syncthreads();  // all waves done with staging LDS
#pragma unroll
      for (int ni = 0; ni < 4; ++ni) {
        int cnl = wc * 64 + ni * 16 + r16;
        float bv = bias2[(n0 & 1023) + cnl];
#pragma unroll
        for (int mi = 0; mi < 4; ++mi) {
          int sl = wr * 64 + mi * 16 + 4 * g;
          union { __bf16 h4[4]; uint2 u; } cv;
#pragma unroll
          for (int j = 0; j < 4; ++j) cv.h4[j] = (__bf16)(acc[mi][ni][j] + bv);
          *(uint2*)&T[cnl * 136 + sl] = cv.u;
        }
      }
      __syncthreads();
      const int bb = m0 >> 11, s0g = m0 & 2047;
      unsigned short* Vt = Cb + 8388608u;
#pragma unroll
      for (int p = 0; p < 8; ++p) {
        int idx = p * 256 + t;
        int cnl = idx >> 4, sch = idx & 15;
        int cng = (n0 & 1023) + cnl;
        int hh = cng >> 6, d = cng & 63;
        short8 v = *(const short8*)&T[cnl * 136 + sch * 8];
        *(short8*)&Vt[(((size_t)((bb * 16 + hh) * 64 + d)) << 11) + s0g + sch * 8] = v;
      }
    }
  } else {
    float* Cf = (float*)Cptr;
#pragma unroll
    for (int ni = 0; ni < 4; ++ni) {
      int col = n0 + wc * 64 + ni * 16 + r16;
      float bv = bias0[col];
#pragma unroll
      for (int mi = 0; mi < 4; ++mi) {
        int rowb = m0 + wr * 64 + mi * 16 + 4 * g;
#pragma unroll
        for (int j = 0; j < 4; ++j)
          Cf[(size_t)(rowb + j) * N + col] = acc[mi][ni][j] + bv;
      }
    }
  }
}

// ---------------- flash attention v11: 32x32 MFMA, kv-split waves, reg-P -------------
// grid 512 x 256. Block = 64 q-rows; sequential halves {mq, 31-mq} -> uniform 17
// 128-wide kv iterations. Wave w owns kv quarter w*32 and BOTH 32-q output tiles.
// P stays in registers via 4 permlane32_swap per q-tile. Cross-wave O-reduction
// through padded LDS once per half. Dbuf K/V staging, vmcnt(0)+barrier per iter.
// Fixed-shift exp2 softmax (m=8, exact). XCD decode keeps K/V L2-resident.
__global__ __launch_bounds__(256, 2) void attn_kernel(
    const unsigned short* __restrict__ Qm, const unsigned short* __restrict__ Km,
    const unsigned short* __restrict__ VtG, unsigned short* __restrict__ Om) {
  const int t = threadIdx.x, lane = t & 63, w = t >> 6;
  const int l31 = lane & 31, hi = lane >> 5;
  const int bid = blockIdx.x;
  const int xk = bid & 7, slot = bid >> 3;
  const int grp = xk * 4 + (slot >> 4);  // (b,h) group, 4 per XCD
  const int mq = slot & 15;
  const int h = grp & 15, b = grp >> 4;

  __shared__ __align__(16) char LB[71680];
  float* R = (float*)LB;
  float* ls = (float*)(LB + 69632);

  const unsigned short* Kbase = Km + (size_t)(b * S_LEN) * DM + h * HD;
  const unsigned short* Vbase = VtG + (size_t)((b * NH + h) * HD) * S_LEN;

  const int kg = ((t & 7) ^ ((t >> 3) & 7)) * 8;
  const int kr0 = t >> 3;
  const int vg = ((t & 15) ^ ((t >> 4) & 15)) * 8;
  const int vr0 = t >> 4;

  auto stage = [&](int cs, int kv0) {
    unsigned short* kd = (unsigned short*)(LB + cs * 16384) + t * 8;
    unsigned short* vd = (unsigned short*)(LB + 32768 + cs * 16384) + t * 8;
#pragma unroll
    for (int p = 0; p < 4; ++p)
      gload_lds16(Kbase + (size_t)(kv0 + kr0 + 32 * p) * DM + kg, kd + 2048 * p);
#pragma unroll
    for (int p = 0; p < 4; ++p)
      gload_lds16(Vbase + (size_t)(vr0 + 16 * p) * S_LEN + kv0 + vg, vd + 2048 * p);
  };

  for (int half = 0; half < 2; ++half) {
    const int T = half ? 31 - mq : mq;
    const int q0 = T * 64;

    bf16x8 qfr[2][4];
#pragma unroll
    for (int qt = 0; qt < 2; ++qt) {
      const unsigned short* Qp =
          Qm + (size_t)(b * S_LEN + q0 + qt * 32 + l31) * DM + h * HD;
#pragma unroll
      for (int kc = 0; kc < 4; ++kc)
        qfr[qt][kc] = *(const bf16x8*)(Qp + kc * 16 + hi * 8);
    }

    f32x16 oacc[2][2] = {};
    float lsum0 = 0.f, lsum1 = 0.f;
    const int ntk = (T >> 1) + 1;

    stage(0, 0);

    for (int kt = 0; kt < ntk; ++kt) {
      const int cs = kt & 1;
      asm volatile("s_waitcnt vmcnt(0)" ::: "memory");
      __builtin_amdgcn_s_barrier();
      if (kt + 1 < ntk) stage(cs ^ 1, (kt + 1) * 128);

      const int kv0w = kt * 128 + w * 32;
      if (kv0w <= q0 + 63) {
        const unsigned short* Ksb = (const unsigned short*)(LB + cs * 16384);
        const unsigned short* Vsb = (const unsigned short*)(LB + 32768 + cs * 16384);

        bf16x8 kf[4];
#pragma unroll
        for (int kc = 0; kc < 4; ++kc)
          kf[kc] = *(const bf16x8*)&Ksb[(w * 32 + l31) * 64 +
                                        (((hi + 2 * kc) ^ (lane & 7)) * 8)];
        bool act0 = false, act1 = false;
        bf16x8 pfr[2][2];
#pragma unroll
        for (int qt = 0; qt < 2; ++qt) {
          const bool act = (kv0w <= q0 + qt * 32 + 31);
          if (qt == 0) act0 = act; else act1 = act;
          if (!act) continue;
          f32x16 st = {};
          __builtin_amdgcn_s_setprio(1);
#pragma unroll
          for (int kc = 0; kc < 4; ++kc) st = mfma32(kf[kc], qfr[qt][kc], st);
          __builtin_amdgcn_s_setprio(0);

          const bool needmask = (kv0w + 31 > q0 + qt * 32);
          const int qg = q0 + qt * 32 + l31;
          float p[16];
          float ps = 0.f;
#pragma unroll
          for (int r = 0; r < 16; ++r) {
            int row = (r & 3) + 8 * (r >> 2) + 4 * hi;
            float v = __builtin_amdgcn_exp2f(st[r] - M2FIX);
            if (needmask && (kv0w + row > qg)) v = 0.f;
            p[r] = v;
            ps += v;
          }
          if (qt == 0) lsum0 += ps; else lsum1 += ps;

          unsigned pw[8];
#pragma unroll
          for (int r = 0; r < 8; ++r) {
            union { __bf16 h2[2]; unsigned u; } cv;
            cv.h2[0] = (__bf16)p[2 * r];
            cv.h2[1] = (__bf16)p[2 * r + 1];
            pw[r] = cv.u;
          }
          {
            auto s0 = __builtin_amdgcn_permlane32_swap(pw[0], pw[2], false, false);
            pw[0] = s0[0]; pw[2] = s0[1];
            auto s1 = __builtin_amdgcn_permlane32_swap(pw[1], pw[3], false, false);
            pw[1] = s1[0]; pw[3] = s1[1];
            auto s2 = __builtin_amdgcn_permlane32_swap(pw[4], pw[6], false, false);
            pw[4] = s2[0]; pw[6] = s2[1];
            auto s3 = __builtin_amdgcn_permlane32_swap(pw[5], pw[7], false, false);
            pw[5] = s3[0]; pw[7] = s3[1];
          }
          union { unsigned u[4]; bf16x8 v; } f0, f1;
          f0.u[0] = pw[0]; f0.u[1] = pw[1]; f0.u[2] = pw[2]; f0.u[3] = pw[3];
          f1.u[0] = pw[4]; f1.u[1] = pw[5]; f1.u[2] = pw[6]; f1.u[3] = pw[7];
          pfr[qt][0] = f0.v;
          pfr[qt][1] = f1.v;
        }

        bf16x8 vf[2][2];
#pragma unroll
        for (int dt = 0; dt < 2; ++dt)
#pragma unroll
          for (int ks = 0; ks < 2; ++ks)
            vf[dt][ks] = *(const bf16x8*)&Vsb[(dt * 32 + l31) * 128 +
                                              (((4 * w + 2 * ks + hi) ^ (lane & 15)) * 8)];
        __builtin_amdgcn_s_setprio(1);
        if (act0) {
#pragma unroll
          for (int dt = 0; dt < 2; ++dt) {
            oacc[dt][0] = mfma32(vf[dt][0], pfr[0][0], oacc[dt][0]);
            oacc[dt][0] = mfma32(vf[dt][1], pfr[0][1], oacc[dt][0]);
          }
        }
        if (act1) {
#pragma unroll
          for (int dt = 0; dt < 2; ++dt) {
            oacc[dt][1] = mfma32(vf[dt][0], pfr[1][0], oacc[dt][1]);
            oacc[dt][1] = mfma32(vf[dt][1], pfr[1][1], oacc[dt][1]);
          }
        }
        __builtin_amdgcn_s_setprio(0);
      }
    }

    __syncthreads();
    float* Rw = R + w * 4352;
#pragma unroll
    for (int dt = 0; dt < 2; ++dt)
#pragma unroll
      for (int qt = 0; qt < 2; ++qt) {
        int q = qt * 32 + l31;
#pragma unroll
        for (int r = 0; r < 16; r += 2) {
          int d = dt * 32 + ((r & 3) + 8 * (r >> 2)) + 4 * hi;
          float2 v2;
          v2.x = oacc[dt][qt][r];
          v2.y = oacc[dt][qt][r + 1];
          *(float2*)&Rw[q * 68 + d] = v2;
        }
      }
    ls[(w * 64 + l31) * 2 + hi] = lsum0;
    ls[(w * 64 + 32 + l31) * 2 + hi] = lsum1;
    __syncthreads();

    const int rq = t >> 2, dq = (t & 3) * 16;
    f32x4 a0 = {}, a1 = {}, a2 = {}, a3 = {};
#pragma unroll
    for (int w4 = 0; w4 < 4; ++w4) {
      const float* Rb = R + w4 * 4352 + rq * 68 + dq;
      a0 += *(const f32x4*)&Rb[0];
      a1 += *(const f32x4*)&Rb[4];
      a2 += *(const f32x4*)&Rb[8];
      a3 += *(const f32x4*)&Rb[12];
    }
    float s = 0.f;
#pragma unroll
    for (int w4 = 0; w4 < 4; ++w4)
      s += ls[(w4 * 64 + rq) * 2] + ls[(w4 * 64 + rq) * 2 + 1];
    float li = 1.0f / s;
    unsigned short* op = Om + (size_t)(b * S_LEN + q0 + rq) * DM + h * HD + dq;
    union { __bf16 hh[8]; uint4 u; } o0, o1;
#pragma unroll
    for (int i = 0; i < 4; ++i) {
      o0.hh[i] = (__bf16)(a0[i] * li);
      o0.hh[4 + i] = (__bf16)(a1[i] * li);
      o1.hh[i] = (__bf16)(a2[i] * li);
      o1.hh[4 + i] = (__bf16)(a3[i] * li);
    }
    *(uint4*)op = o0.u;
    *(uint4*)(op + 8) = o1.u;
    __syncthreads();
  }
}

extern "C" void kernel_launch(void* const* d_in, const int* in_sizes, int n_in,
                              void* d_out, int out_size, void* d_ws, size_t ws_size,
                              hipStream_t stream) {
  (void)in_sizes; (void)n_in; (void)out_size; (void)ws_size;
  const float* x  = (const float*)d_in[0];
  const float* WQ = (const float*)d_in[1];
  const float* WK = (const float*)d_in[2];
  const float* WV = (const float*)d_in[3];
  const float* WO = (const float*)d_in[4];
  const float* bQ = (const float*)d_in[5];
  const float* bK = (const float*)d_in[6];
  const float* bV = (const float*)d_in[7];
  const float* bO = (const float*)d_in[8];

  char* ws = (char*)d_ws;
  unsigned short* xb  = (unsigned short*)(ws);               // 8 MiB (x bf16)
  unsigned short* wt  = (unsigned short*)(ws + (8u << 20));  // 8 MiB (Wq|Wk|Wv|Wo)^T
  unsigned short* qb  = (unsigned short*)(ws + (16u << 20)); // 24 MiB (Q | K | V^T)
  unsigned short* hsb = (unsigned short*)(ws + (40u << 20)); // 8 MiB (attn out)

  cast_bf16_kernel<<<2048, 256, 0, stream>>>(x, xb);
  transpose_cast_kernel<<<dim3(32, 32, 4), 256, 0, stream>>>(WQ, WK, WV, WO, wt);
  // fused QKV projection: N = 3072; Q pre-scaled; V^T via LDS-transposed epilogue
  gemm_bt_kernel<0><<<dim3(24, 32), 256, 0, stream>>>(
      xb, wt, (void*)qb, bQ, bK, bV, M_ROWS, 3072, DM);
  attn_kernel<<<512, 256, 0, stream>>>(qb, qb + 4194304u, qb + 8388608u, hsb);
  // output projection: f32 out
  gemm_bt_kernel<1><<<dim3(8, 32), 256, 0, stream>>>(
      hsb, wt + 3u * 1048576u, d_out, bO, nullptr, nullptr, M_ROWS, DM, DM);
}